// Round 24
// baseline (461.111 us; speedup 1.0000x reference)
//
#include <hip/hip_runtime.h>
#include <hip/hip_bf16.h>

typedef _Float16 f16x8 __attribute__((ext_vector_type(8)));
typedef unsigned short u16x8 __attribute__((ext_vector_type(8)));
typedef float f32x4 __attribute__((ext_vector_type(4)));
typedef unsigned int u32x4 __attribute__((ext_vector_type(4)));

static __device__ __forceinline__ unsigned short h2u(_Float16 h) {
    return __builtin_bit_cast(unsigned short, h);
}
static __device__ __forceinline__ float fast_tanh(float x) {
    float e = __expf(2.0f * x);
    return 1.0f - 2.0f / (e + 1.0f);
}

// ---------------- ws layout (bytes) ----------------
//   wlin_h : u16 [320][512]   @ 0        (327680)
//   wlin_l : u16 [320][512]   @ 327680   (327680)
//   (unused)                  @ 655360   (261120)
//   wnl_h  : u16 [255][256]   @ 916480   (130560)
//   wnl_l  : u16 [255][256]   @ 1047040  (130560)
//   wout_h : u16 [64][256]    @ 1177600  (32768)
//   wout_l : u16 [64][256]    @ 1210368  (32768)
//   wcol   : f32 [8][496]     @ 1243136  (15872)
//   linc   : f32 [65536][256] @ 1259008  (67108864)  COLUMN-SHIFTED lin
//   lino   : f32 [65536][64]  @ 68367872 (16777216)  total 85145088
__global__ void cascade_prep(const float* __restrict__ W_lin,
                             const float* __restrict__ W_nl,
                             const float* __restrict__ W_out,
                             unsigned short* __restrict__ wlin_h,
                             unsigned short* __restrict__ wlin_l,
                             unsigned short* __restrict__ wnl_h,
                             unsigned short* __restrict__ wnl_l,
                             unsigned short* __restrict__ wout_h,
                             unsigned short* __restrict__ wout_l,
                             float* __restrict__ wcol) {
    int idx = blockIdx.x * blockDim.x + threadIdx.x;
    int stride = gridDim.x * blockDim.x;
    for (int i = idx; i < 320 * 512; i += stride) {
        int n = i >> 9, k = i & 511;
        float w = W_lin[k * 320 + n];
        _Float16 h = (_Float16)w;
        wlin_h[i] = h2u(h);
        wlin_l[i] = h2u((_Float16)(w - (float)h));
    }
    for (int i = idx; i < 255 * 256; i += stride) {
        int r = i >> 8, k = i & 255;
        float w = (k <= r) ? W_nl[i] : 0.0f;
        _Float16 h = (_Float16)w;
        wnl_h[i] = h2u(h);
        wnl_l[i] = h2u((_Float16)(w - (float)h));
    }
    for (int i = idx; i < 64 * 256; i += stride) {
        float w = W_out[i];
        _Float16 h = (_Float16)w;
        wout_h[i] = h2u(h);
        wout_l[i] = h2u((_Float16)(w - (float)h));
    }
    for (int i = idx; i < 256; i += stride) {
        int b = i >> 5, u = i & 31;
        float* dst = wcol + b * 496 + (31 * u - (u * (u - 1)) / 2);
        for (int j = u + 1; j < 32; ++j)
            dst[j - u - 1] = W_nl[(size_t)(b * 32 + j - 1) * 256 + b * 32 + u];
    }
}

// ---------------- kernel A: lin = x @ W_lin (fp16-split) ----------------
// Writes linc COLUMN-SHIFTED: linc[r][c+1] = lin[r][c] (c<255), linc[r][0] =
// lin[r][0]. casc's conacc[j] = lin[j-1] + contrib[j] aligns per-column.
__global__ __launch_bounds__(512, 1) void lin_gemm(
    const float* __restrict__ x,
    const unsigned short* __restrict__ wlin_h,
    const unsigned short* __restrict__ wlin_l,
    float* __restrict__ linc,
    float* __restrict__ lino) {

    __shared__ _Float16 bufH[2][16 * 520];
    __shared__ _Float16 bufL[2][16 * 520];

    const int tid = threadIdx.x;
    const int wv  = tid >> 6;
    const int l15 = tid & 15;
    const int g   = (tid & 63) >> 4;
    const int s = (blockIdx.x & 7) * 64 + (blockIdx.x >> 3);   // XCD chunking
    const long row0 = (long)s * 128;

    f16x8 xfh[16], xfl[16];
    {
        const float* xp = x + (row0 + wv * 16 + l15) * 512 + g * 8;
        #pragma unroll
        for (int ks = 0; ks < 16; ++ks) {
            float4 p0 = *reinterpret_cast<const float4*>(xp + ks * 32);
            float4 p1 = *reinterpret_cast<const float4*>(xp + ks * 32 + 4);
            float av[8] = {p0.x, p0.y, p0.z, p0.w, p1.x, p1.y, p1.z, p1.w};
            f16x8 fh, fl;
            #pragma unroll
            for (int e = 0; e < 8; ++e) {
                _Float16 hh = (_Float16)av[e];
                fh[e] = hh;
                fl[e] = (_Float16)(av[e] - (float)hh);
            }
            xfh[ks] = fh;
            xfl[ks] = fl;
        }
    }

    u16x8 rh[2], rl[2];
    #define STAGE_LOAD(nt)                                                     \
        {                                                                      \
            _Pragma("unroll")                                                  \
            for (int it = 0; it < 2; ++it) {                                   \
                int flat = it * 4096 + tid * 8;                                \
                int r = flat >> 9, c = flat & 511;                             \
                rh[it] = *reinterpret_cast<const u16x8*>(                      \
                    wlin_h + (size_t)((nt) * 16 + r) * 512 + c);               \
                rl[it] = *reinterpret_cast<const u16x8*>(                      \
                    wlin_l + (size_t)((nt) * 16 + r) * 512 + c);               \
            }                                                                  \
        }
    #define STAGE_WRITE(buf)                                                   \
        {                                                                      \
            _Pragma("unroll")                                                  \
            for (int it = 0; it < 2; ++it) {                                   \
                int flat = it * 4096 + tid * 8;                                \
                int r = flat >> 9, c = flat & 511;                             \
                *reinterpret_cast<u16x8*>(&bufH[buf][r * 520 + c]) =           \
                    __builtin_bit_cast(u16x8, rh[it]);                         \
                *reinterpret_cast<u16x8*>(&bufL[buf][r * 520 + c]) =           \
                    __builtin_bit_cast(u16x8, rl[it]);                         \
            }                                                                  \
        }

    STAGE_LOAD(0);
    STAGE_WRITE(0);
    __syncthreads();

    int cur = 0;
    for (int nt = 0; nt < 20; ++nt) {
        if (nt < 19) STAGE_LOAD(nt + 1);

        f32x4 acc = (f32x4){0.f, 0.f, 0.f, 0.f};
        if (nt < 16) {
            #pragma unroll
            for (int ks = 0; ks < 16; ++ks) {
                f16x8 bh = *reinterpret_cast<const f16x8*>(
                    &bufH[cur][l15 * 520 + ks * 32 + g * 8]);
                f16x8 bl = *reinterpret_cast<const f16x8*>(
                    &bufL[cur][l15 * 520 + ks * 32 + g * 8]);
                acc = __builtin_amdgcn_mfma_f32_16x16x32_f16(xfh[ks], bh, acc, 0, 0, 0);
                acc = __builtin_amdgcn_mfma_f32_16x16x32_f16(xfl[ks], bh, acc, 0, 0, 0);
                acc = __builtin_amdgcn_mfma_f32_16x16x32_f16(xfh[ks], bl, acc, 0, 0, 0);
            }
            int c = nt * 16 + l15;
            #pragma unroll
            for (int j = 0; j < 4; ++j) {
                long row = row0 + wv * 16 + g * 4 + j;
                if (c < 255) linc[row * 256 + c + 1] = acc[j];
                if (c == 0)  linc[row * 256] = acc[j];
            }
        } else {
            #pragma unroll
            for (int ks = 0; ks < 16; ++ks) {
                f16x8 bh = *reinterpret_cast<const f16x8*>(
                    &bufH[cur][l15 * 520 + ks * 32 + g * 8]);
                acc = __builtin_amdgcn_mfma_f32_16x16x32_f16(xfh[ks], bh, acc, 0, 0, 0);
            }
            #pragma unroll
            for (int j = 0; j < 4; ++j)
                lino[(row0 + wv * 16 + g * 4 + j) * 64 + (nt - 16) * 16 + l15] = acc[j];
        }

        if (nt < 19) STAGE_WRITE(cur ^ 1);
        __syncthreads();
        cur ^= 1;
    }
    #undef STAGE_LOAD
    #undef STAGE_WRITE
}

// unpack packed h|l u32x4 pair -> fp16 hi / lo MFMA A-fragments
static __device__ __forceinline__ void unpack_pf(u32x4 a0, u32x4 a1,
                                                 f16x8* ah, f16x8* al) {
    u32x4 hx, lx;
    hx[0] = (a0[0] & 0xffffu) | (a0[1] << 16);
    hx[1] = (a0[2] & 0xffffu) | (a0[3] << 16);
    hx[2] = (a1[0] & 0xffffu) | (a1[1] << 16);
    hx[3] = (a1[2] & 0xffffu) | (a1[3] << 16);
    lx[0] = (a0[0] >> 16) | (a0[1] & 0xffff0000u);
    lx[1] = (a0[2] >> 16) | (a0[3] & 0xffff0000u);
    lx[2] = (a1[0] >> 16) | (a1[1] & 0xffff0000u);
    lx[3] = (a1[2] >> 16) | (a1[3] & 0xffff0000u);
    *ah = __builtin_bit_cast(f16x8, hx);
    *al = __builtin_bit_cast(f16x8, lx);
}

// ---------------- kernel B: wave-specialized forward cascade ----------------
// v12: 128 threads = 2 waves. wave0 = serial producer, wave1 = pass consumer.
// Region b: phase A {wave0: stage wslab(b) || wave1: URGENT pass(b-1) for the
// next serial window nt=2b,2b+1} -> barrier -> phase B {wave0: serial(b) ||
// wave1: DEFERRED pass(b-1), nt>=2b+2} -> barrier. The deferred pass's
// load/MFMA/LDS-rmw latency runs on a DIFFERENT wave concurrent with the
// serial chain (m114: co-scheduled waves overlap, time ~= max not sum).
// Per-column pass order stays b-ascending -> bit-identical numerics.
// Disjointness: serial(b) cols [32b,32b+32) vs deferred cols >= 32(b+1).
// Each wave's register path <= r21's 116 -> VGPR <= 128 (the r23 lesson).
// LDS 18.9 KB -> 8 blocks/CU = 16 waves/CU. Grid 4096, XCD chunk 512.
__global__ __launch_bounds__(128) void cascade_casc(
    const float* __restrict__ linc,
    const float* __restrict__ lino,
    const float* __restrict__ wcol,
    const unsigned short* __restrict__ wnl_h,
    const unsigned short* __restrict__ wnl_l,
    const unsigned short* __restrict__ wout_h,
    const unsigned short* __restrict__ wout_l,
    float* __restrict__ out) {

    __shared__ float conacc[16 * 260];   // [row][col], stride 260
    __shared__ float wslab[500];         // intra-block triangle slab
    unsigned int* conp = reinterpret_cast<unsigned int*>(conacc);

    const int tid = threadIdx.x;
    const int wv  = tid >> 6;        // 0 = serial wave, 1 = pass wave
    const int ll  = tid & 63;
    const int l15 = ll & 15;
    const int g   = ll >> 4;         // MFMA k-group / serial replica id
    const int s = (blockIdx.x & 7) * 512 + (blockIdx.x >> 3);   // XCD chunking
    const long row0 = (long)s * 16;

    // ===== init conacc = linc (shifted lin): 4096 floats / 128 lanes =====
    #pragma unroll
    for (int it = 0; it < 8; ++it) {
        int flat = it * 512 + tid * 4;
        int rr = flat >> 8, c4 = flat & 255;
        float4 v = *reinterpret_cast<const float4*>(linc + (row0 + rr) * 256 + c4);
        *reinterpret_cast<float4*>(&conacc[rr * 260 + c4]) = v;
    }
    __syncthreads();

    // one nt-update using fragments AH/AL of source block bs (pass wave only)
    #define NT_UPDATE(bs, nt, AH, AL)                                          \
        {                                                                      \
            const size_t wrow = (size_t)((nt) * 16 + l15 - 1) * 256            \
                                + (bs) * 32 + g * 8;                           \
            f16x8 bh_ = __builtin_bit_cast(f16x8,                              \
                *reinterpret_cast<const u16x8*>(wnl_h + wrow));                \
            f16x8 bl_ = __builtin_bit_cast(f16x8,                              \
                *reinterpret_cast<const u16x8*>(wnl_l + wrow));                \
            f32x4 d_ = (f32x4){0.f, 0.f, 0.f, 0.f};                            \
            d_ = __builtin_amdgcn_mfma_f32_16x16x32_f16(AH, bh_, d_, 0, 0, 0); \
            d_ = __builtin_amdgcn_mfma_f32_16x16x32_f16(AL, bh_, d_, 0, 0, 0); \
            d_ = __builtin_amdgcn_mfma_f32_16x16x32_f16(AH, bl_, d_, 0, 0, 0); \
            _Pragma("unroll")                                                  \
            for (int jj_ = 0; jj_ < 4; ++jj_) {                                \
                int idx_ = (g * 4 + jj_) * 260 + (nt) * 16 + l15;              \
                conacc[idx_] += d_[jj_];                                       \
            }                                                                  \
        }

    #pragma unroll
    for (int b = 0; b < 8; ++b) {
        f16x8 pah = {}, pal = {};
        // ---- phase A: wave0 stages wslab(b) || wave1 urgent pass(b-1) ----
        if (wv == 0) {
            int i0 = ll * 4;
            if (i0 < 496) {
                float4 v0 = *reinterpret_cast<const float4*>(wcol + b * 496 + i0);
                *reinterpret_cast<float4*>(&wslab[i0]) = v0;
            }
            int i1 = 256 + ll * 4;
            if (i1 < 496) {
                float4 v1 = *reinterpret_cast<const float4*>(wcol + b * 496 + i1);
                *reinterpret_cast<float4*>(&wslab[i1]) = v1;
            }
        } else if (b >= 1) {
            const unsigned int* p = &conp[l15 * 260 + (b - 1) * 32 + g * 8];
            unpack_pf(*reinterpret_cast<const u32x4*>(p),
                      *reinterpret_cast<const u32x4*>(p + 4), &pah, &pal);
            NT_UPDATE(b - 1, 2 * b, pah, pal);
            NT_UPDATE(b - 1, 2 * b + 1, pah, pal);
        }
        __syncthreads();   // wslab staged; window b's pass updates complete

        // ---- phase B: wave0 serial(b) || wave1 deferred pass(b-1) ----
        if (wv == 0) {
            float acc[32];
            #pragma unroll
            for (int j = 0; j < 32; ++j) acc[j] = 0.0f;
            #pragma unroll
            for (int u8 = 0; u8 < 4; ++u8) {
                float4 cw0 = *reinterpret_cast<const float4*>(&conacc[l15 * 260 + b * 32 + u8 * 8]);
                float4 cw1 = *reinterpret_cast<const float4*>(&conacc[l15 * 260 + b * 32 + u8 * 8 + 4]);
                float conw[8] = {cw0.x, cw0.y, cw0.z, cw0.w, cw1.x, cw1.y, cw1.z, cw1.w};
                unsigned int pk[8];
                #pragma unroll
                for (int v = 0; v < 8; ++v) {
                    const int u = u8 * 8 + v;
                    float vv = acc[u] + conw[v] + 1.0f;
                    float tv = fast_tanh(vv);
                    _Float16 hv = (_Float16)tv;
                    _Float16 lo = (_Float16)(tv - (float)hv);
                    pk[v] = (unsigned int)h2u(hv) | ((unsigned int)h2u(lo) << 16);
                    const float* wu = wslab + (31 * u - (u * (u - 1)) / 2);
                    #pragma unroll
                    for (int j = u + 1; j < 32; ++j)
                        acc[j] = fmaf(tv, wu[j - u - 1], acc[j]);
                }
                if (ll < 16) {
                    *reinterpret_cast<u32x4*>(&conp[l15 * 260 + b * 32 + u8 * 8]) =
                        (u32x4){pk[0], pk[1], pk[2], pk[3]};
                    *reinterpret_cast<u32x4*>(&conp[l15 * 260 + b * 32 + u8 * 8 + 4]) =
                        (u32x4){pk[4], pk[5], pk[6], pk[7]};
                }
            }
        } else if (b >= 1) {
            for (int nt = 2 * b + 2; nt < 16; ++nt)
                NT_UPDATE(b - 1, nt, pah, pal);
        }
        __syncthreads();   // th_b packed + deferred(b-1) complete
    }
    #undef NT_UPDATE

    // ===== stage 3: out = tanh @ W_out^T + lin_o + 1; wave wv does n = 2wv, 2wv+1 =====
    #pragma unroll
    for (int nn = 0; nn < 2; ++nn) {
        const int n = wv * 2 + nn;
        f32x4 acc = (f32x4){0.f, 0.f, 0.f, 0.f};
        #pragma unroll
        for (int kc = 0; kc < 8; ++kc) {
            const unsigned int* p = &conp[l15 * 260 + kc * 32 + g * 8];
            f16x8 ah, al;
            unpack_pf(*reinterpret_cast<const u32x4*>(p),
                      *reinterpret_cast<const u32x4*>(p + 4), &ah, &al);
            const size_t wrow = (size_t)(n * 16 + l15) * 256 + kc * 32 + g * 8;
            f16x8 bh = __builtin_bit_cast(f16x8, *reinterpret_cast<const u16x8*>(wout_h + wrow));
            f16x8 bl = __builtin_bit_cast(f16x8, *reinterpret_cast<const u16x8*>(wout_l + wrow));
            acc = __builtin_amdgcn_mfma_f32_16x16x32_f16(ah, bh, acc, 0, 0, 0);
            acc = __builtin_amdgcn_mfma_f32_16x16x32_f16(al, bh, acc, 0, 0, 0);
            acc = __builtin_amdgcn_mfma_f32_16x16x32_f16(ah, bl, acc, 0, 0, 0);
        }
        #pragma unroll
        for (int j = 0; j < 4; ++j) {
            long rr = row0 + g * 4 + j;
            int c = n * 16 + l15;
            out[rr * 64 + c] = acc[j] + lino[rr * 64 + c] + 1.0f;
        }
    }
}

extern "C" void kernel_launch(void* const* d_in, const int* in_sizes, int n_in,
                              void* d_out, int out_size, void* d_ws, size_t ws_size,
                              hipStream_t stream) {
    (void)in_sizes; (void)n_in; (void)out_size; (void)ws_size;
    const float* x     = (const float*)d_in[0];
    const float* W_lin = (const float*)d_in[1];
    const float* W_nl  = (const float*)d_in[2];
    const float* W_out = (const float*)d_in[3];
    float* out = (float*)d_out;

    char* ws = (char*)d_ws;
    unsigned short* wlin_h = (unsigned short*)(ws);
    unsigned short* wlin_l = (unsigned short*)(ws + 327680);
    unsigned short* wnl_h  = (unsigned short*)(ws + 916480);
    unsigned short* wnl_l  = (unsigned short*)(ws + 1047040);
    unsigned short* wout_h = (unsigned short*)(ws + 1177600);
    unsigned short* wout_l = (unsigned short*)(ws + 1210368);
    float*          wcol   = (float*)(ws + 1243136);
    float*          linc   = (float*)(ws + 1259008);
    float*          lino   = (float*)(ws + 68367872);

    cascade_prep<<<256, 256, 0, stream>>>(W_lin, W_nl, W_out,
                                          wlin_h, wlin_l, wnl_h, wnl_l,
                                          wout_h, wout_l, wcol);
    lin_gemm<<<512, 512, 0, stream>>>(x, wlin_h, wlin_l, linc, lino);
    cascade_casc<<<4096, 128, 0, stream>>>(linc, lino, wcol,
                                           wnl_h, wnl_l, wout_h, wout_l, out);
}

// Round 25
// 237.243 us; speedup vs baseline: 1.9436x; 1.9436x over previous
//
#include <hip/hip_runtime.h>
#include <hip/hip_bf16.h>

typedef _Float16 f16x8 __attribute__((ext_vector_type(8)));
typedef unsigned short u16x8 __attribute__((ext_vector_type(8)));
typedef float f32x4 __attribute__((ext_vector_type(4)));
typedef unsigned int u32x4 __attribute__((ext_vector_type(4)));

static __device__ __forceinline__ unsigned short h2u(_Float16 h) {
    return __builtin_bit_cast(unsigned short, h);
}
static __device__ __forceinline__ float fast_tanh(float x) {
    float e = __expf(2.0f * x);
    return 1.0f - 2.0f / (e + 1.0f);
}

// ---------------- ws layout (bytes) ----------------
//   wlin_h : u16 [320][512]   @ 0        (327680)
//   wlin_l : u16 [320][512]   @ 327680   (327680)
//   (unused)                  @ 655360   (261120)
//   wnl_h  : u16 [255][256]   @ 916480   (130560)
//   wnl_l  : u16 [255][256]   @ 1047040  (130560)
//   wout_h : u16 [64][256]    @ 1177600  (32768)
//   wout_l : u16 [64][256]    @ 1210368  (32768)
//   wcol   : f32 [8][496]     @ 1243136  (15872)
//   linc   : f32 [65536][256] @ 1259008  (67108864)  COLUMN-SHIFTED lin
//   lino   : f32 [65536][64]  @ 68367872 (16777216)  total 85145088
__global__ void cascade_prep(const float* __restrict__ W_lin,
                             const float* __restrict__ W_nl,
                             const float* __restrict__ W_out,
                             unsigned short* __restrict__ wlin_h,
                             unsigned short* __restrict__ wlin_l,
                             unsigned short* __restrict__ wnl_h,
                             unsigned short* __restrict__ wnl_l,
                             unsigned short* __restrict__ wout_h,
                             unsigned short* __restrict__ wout_l,
                             float* __restrict__ wcol) {
    int idx = blockIdx.x * blockDim.x + threadIdx.x;
    int stride = gridDim.x * blockDim.x;
    for (int i = idx; i < 320 * 512; i += stride) {
        int n = i >> 9, k = i & 511;
        float w = W_lin[k * 320 + n];
        _Float16 h = (_Float16)w;
        wlin_h[i] = h2u(h);
        wlin_l[i] = h2u((_Float16)(w - (float)h));
    }
    for (int i = idx; i < 255 * 256; i += stride) {
        int r = i >> 8, k = i & 255;
        float w = (k <= r) ? W_nl[i] : 0.0f;
        _Float16 h = (_Float16)w;
        wnl_h[i] = h2u(h);
        wnl_l[i] = h2u((_Float16)(w - (float)h));
    }
    for (int i = idx; i < 64 * 256; i += stride) {
        float w = W_out[i];
        _Float16 h = (_Float16)w;
        wout_h[i] = h2u(h);
        wout_l[i] = h2u((_Float16)(w - (float)h));
    }
    for (int i = idx; i < 256; i += stride) {
        int b = i >> 5, u = i & 31;
        float* dst = wcol + b * 496 + (31 * u - (u * (u - 1)) / 2);
        for (int j = u + 1; j < 32; ++j)
            dst[j - u - 1] = W_nl[(size_t)(b * 32 + j - 1) * 256 + b * 32 + u];
    }
}

// ---------------- kernel A: lin = x @ W_lin (fp16-split) ----------------
// Writes linc COLUMN-SHIFTED: linc[r][c+1] = lin[r][c] (c<255), linc[r][0] =
// lin[r][0]. casc's conacc[j] = lin[j-1] + contrib[j] aligns per-column.
__global__ __launch_bounds__(512, 1) void lin_gemm(
    const float* __restrict__ x,
    const unsigned short* __restrict__ wlin_h,
    const unsigned short* __restrict__ wlin_l,
    float* __restrict__ linc,
    float* __restrict__ lino) {

    __shared__ _Float16 bufH[2][16 * 520];
    __shared__ _Float16 bufL[2][16 * 520];

    const int tid = threadIdx.x;
    const int wv  = tid >> 6;
    const int l15 = tid & 15;
    const int g   = (tid & 63) >> 4;
    const int s = (blockIdx.x & 7) * 64 + (blockIdx.x >> 3);   // XCD chunking
    const long row0 = (long)s * 128;

    f16x8 xfh[16], xfl[16];
    {
        const float* xp = x + (row0 + wv * 16 + l15) * 512 + g * 8;
        #pragma unroll
        for (int ks = 0; ks < 16; ++ks) {
            float4 p0 = *reinterpret_cast<const float4*>(xp + ks * 32);
            float4 p1 = *reinterpret_cast<const float4*>(xp + ks * 32 + 4);
            float av[8] = {p0.x, p0.y, p0.z, p0.w, p1.x, p1.y, p1.z, p1.w};
            f16x8 fh, fl;
            #pragma unroll
            for (int e = 0; e < 8; ++e) {
                _Float16 hh = (_Float16)av[e];
                fh[e] = hh;
                fl[e] = (_Float16)(av[e] - (float)hh);
            }
            xfh[ks] = fh;
            xfl[ks] = fl;
        }
    }

    u16x8 rh[2], rl[2];
    #define STAGE_LOAD(nt)                                                     \
        {                                                                      \
            _Pragma("unroll")                                                  \
            for (int it = 0; it < 2; ++it) {                                   \
                int flat = it * 4096 + tid * 8;                                \
                int r = flat >> 9, c = flat & 511;                             \
                rh[it] = *reinterpret_cast<const u16x8*>(                      \
                    wlin_h + (size_t)((nt) * 16 + r) * 512 + c);               \
                rl[it] = *reinterpret_cast<const u16x8*>(                      \
                    wlin_l + (size_t)((nt) * 16 + r) * 512 + c);               \
            }                                                                  \
        }
    #define STAGE_WRITE(buf)                                                   \
        {                                                                      \
            _Pragma("unroll")                                                  \
            for (int it = 0; it < 2; ++it) {                                   \
                int flat = it * 4096 + tid * 8;                                \
                int r = flat >> 9, c = flat & 511;                             \
                *reinterpret_cast<u16x8*>(&bufH[buf][r * 520 + c]) =           \
                    __builtin_bit_cast(u16x8, rh[it]);                         \
                *reinterpret_cast<u16x8*>(&bufL[buf][r * 520 + c]) =           \
                    __builtin_bit_cast(u16x8, rl[it]);                         \
            }                                                                  \
        }

    STAGE_LOAD(0);
    STAGE_WRITE(0);
    __syncthreads();

    int cur = 0;
    for (int nt = 0; nt < 20; ++nt) {
        if (nt < 19) STAGE_LOAD(nt + 1);

        f32x4 acc = (f32x4){0.f, 0.f, 0.f, 0.f};
        if (nt < 16) {
            #pragma unroll
            for (int ks = 0; ks < 16; ++ks) {
                f16x8 bh = *reinterpret_cast<const f16x8*>(
                    &bufH[cur][l15 * 520 + ks * 32 + g * 8]);
                f16x8 bl = *reinterpret_cast<const f16x8*>(
                    &bufL[cur][l15 * 520 + ks * 32 + g * 8]);
                acc = __builtin_amdgcn_mfma_f32_16x16x32_f16(xfh[ks], bh, acc, 0, 0, 0);
                acc = __builtin_amdgcn_mfma_f32_16x16x32_f16(xfl[ks], bh, acc, 0, 0, 0);
                acc = __builtin_amdgcn_mfma_f32_16x16x32_f16(xfh[ks], bl, acc, 0, 0, 0);
            }
            int c = nt * 16 + l15;
            #pragma unroll
            for (int j = 0; j < 4; ++j) {
                long row = row0 + wv * 16 + g * 4 + j;
                if (c < 255) linc[row * 256 + c + 1] = acc[j];
                if (c == 0)  linc[row * 256] = acc[j];
            }
        } else {
            #pragma unroll
            for (int ks = 0; ks < 16; ++ks) {
                f16x8 bh = *reinterpret_cast<const f16x8*>(
                    &bufH[cur][l15 * 520 + ks * 32 + g * 8]);
                acc = __builtin_amdgcn_mfma_f32_16x16x32_f16(xfh[ks], bh, acc, 0, 0, 0);
            }
            #pragma unroll
            for (int j = 0; j < 4; ++j)
                lino[(row0 + wv * 16 + g * 4 + j) * 64 + (nt - 16) * 16 + l15] = acc[j];
        }

        if (nt < 19) STAGE_WRITE(cur ^ 1);
        __syncthreads();
        cur ^= 1;
    }
    #undef STAGE_LOAD
    #undef STAGE_WRITE
}

// unpack packed h|l u32x4 pair -> fp16 hi / lo MFMA A-fragments
static __device__ __forceinline__ void unpack_pf(u32x4 a0, u32x4 a1,
                                                 f16x8* ah, f16x8* al) {
    u32x4 hx, lx;
    hx[0] = (a0[0] & 0xffffu) | (a0[1] << 16);
    hx[1] = (a0[2] & 0xffffu) | (a0[3] << 16);
    hx[2] = (a1[0] & 0xffffu) | (a1[1] << 16);
    hx[3] = (a1[2] & 0xffffu) | (a1[3] << 16);
    lx[0] = (a0[0] >> 16) | (a0[1] & 0xffff0000u);
    lx[1] = (a0[2] >> 16) | (a0[3] & 0xffff0000u);
    lx[2] = (a1[0] >> 16) | (a1[1] & 0xffff0000u);
    lx[3] = (a1[2] >> 16) | (a1[3] & 0xffff0000u);
    *ah = __builtin_bit_cast(f16x8, hx);
    *al = __builtin_bit_cast(f16x8, lx);
}

// ---------------- kernel B: forward-accumulating cascade, 16 rows/block ----------------
// FINAL (= r21, best stable): wslab LDS broadcast weights in the serial chain;
// T14 wnl prefetch (neutral but harmless); separate pass phase. The serial
// cascade survives ONLY as a 1-wave, unconstrained-bounds, <=~120-VGPR body:
//  - min-waves caps (r7 (64,4), r16 (256,4)) -> allocator demotes to scratch
//  - >128 VGPR (r23 batching) -> occupancy tier halves
//  - divergent wave roles (r24) -> union allocation demotes
//  - s_load serial weights (r20) -> lgkmcnt stalls in the tanh chain
// 16 rows/block, 8 independent blocks/CU, grid 4096, XCD chunk 512.
__global__ __launch_bounds__(64) void cascade_casc(
    const float* __restrict__ linc,
    const float* __restrict__ lino,
    const float* __restrict__ wcol,
    const unsigned short* __restrict__ wnl_h,
    const unsigned short* __restrict__ wnl_l,
    const unsigned short* __restrict__ wout_h,
    const unsigned short* __restrict__ wout_l,
    float* __restrict__ out) {

    __shared__ float conacc[16 * 260];   // [row][col], stride 260
    __shared__ float wslab[500];         // intra-block triangle slab
    unsigned int* conp = reinterpret_cast<unsigned int*>(conacc);

    const int l   = threadIdx.x;
    const int l15 = l & 15;
    const int g   = l >> 4;          // MFMA k-group / serial replica id
    const int s = (blockIdx.x & 7) * 512 + (blockIdx.x >> 3);   // XCD chunking
    const long row0 = (long)s * 16;

    // ===== init conacc = linc (shifted lin): 4096 floats / 64 lanes =====
    #pragma unroll
    for (int it = 0; it < 16; ++it) {
        int flat = it * 256 + l * 4;
        int rr = flat >> 8, c4 = flat & 255;
        float4 v = *reinterpret_cast<const float4*>(linc + (row0 + rr) * 256 + c4);
        *reinterpret_cast<float4*>(&conacc[rr * 260 + c4]) = v;
    }
    __syncthreads();

    for (int b = 0; b < 8; ++b) {
        // --- T14: prefetch first 4 nt-iterations' wnl fragments (static idx) ---
        u16x8 pbh[4], pbl[4];
        if (b < 7) {
            #pragma unroll
            for (int q = 0; q < 4; ++q) {
                int nt = 2 * (b + 1) + q;
                if (nt < 16) {
                    const size_t wrow = (size_t)(nt * 16 + l15 - 1) * 256 + b * 32 + g * 8;
                    pbh[q] = *reinterpret_cast<const u16x8*>(wnl_h + wrow);
                    pbl[q] = *reinterpret_cast<const u16x8*>(wnl_l + wrow);
                }
            }
        }

        // --- stage wcol slab for block b (broadcast ds_read path) ---
        {
            int i0 = l * 4;
            float4 v0 = *reinterpret_cast<const float4*>(wcol + b * 496 + i0);
            *reinterpret_cast<float4*>(&wslab[i0]) = v0;      // i0 in [0,252]
            int i1 = 256 + l * 4;
            if (i1 < 496) {
                float4 v1 = *reinterpret_cast<const float4*>(wcol + b * 496 + i1);
                *reinterpret_cast<float4*>(&wslab[i1]) = v1;
            }
        }
        __syncthreads();   // wslab ready; prev MFMA-pass conacc updates visible

        // --- serial 32 steps (4 replicas of each row's chain) ---
        float acc[32];
        #pragma unroll
        for (int j = 0; j < 32; ++j) acc[j] = 0.0f;
        #pragma unroll
        for (int u8 = 0; u8 < 4; ++u8) {
            float4 cw0 = *reinterpret_cast<const float4*>(&conacc[l15 * 260 + b * 32 + u8 * 8]);
            float4 cw1 = *reinterpret_cast<const float4*>(&conacc[l15 * 260 + b * 32 + u8 * 8 + 4]);
            float conw[8] = {cw0.x, cw0.y, cw0.z, cw0.w, cw1.x, cw1.y, cw1.z, cw1.w};
            unsigned int pk[8];
            #pragma unroll
            for (int v = 0; v < 8; ++v) {
                const int u = u8 * 8 + v;
                float vv = acc[u] + conw[v] + 1.0f;
                float tv = fast_tanh(vv);
                _Float16 hv = (_Float16)tv;
                _Float16 lo = (_Float16)(tv - (float)hv);
                pk[v] = (unsigned int)h2u(hv) | ((unsigned int)h2u(lo) << 16);
                const float* wu = wslab + (31 * u - (u * (u - 1)) / 2);
                #pragma unroll
                for (int j = u + 1; j < 32; ++j)
                    acc[j] = fmaf(tv, wu[j - u - 1], acc[j]);
            }
            // overwrite consumed cols with packed th (one replica writes)
            if (l < 16) {
                *reinterpret_cast<u32x4*>(&conp[l15 * 260 + b * 32 + u8 * 8]) =
                    (u32x4){pk[0], pk[1], pk[2], pk[3]};
                *reinterpret_cast<u32x4*>(&conp[l15 * 260 + b * 32 + u8 * 8 + 4]) =
                    (u32x4){pk[4], pk[5], pk[6], pk[7]};
            }
        }
        __syncthreads();   // packed th visible to all lanes

        // --- forward MFMA: conacc[:, 32(b+1):] += th_b @ Wnl^T ---
        if (b < 7) {
            f16x8 ah, al;
            {
                const unsigned int* p = &conp[l15 * 260 + b * 32 + g * 8];
                unpack_pf(*reinterpret_cast<const u32x4*>(p),
                          *reinterpret_cast<const u32x4*>(p + 4), &ah, &al);
            }
            // first up-to-4 nt from prefetched registers (static unroll)
            #pragma unroll
            for (int q = 0; q < 4; ++q) {
                int nt = 2 * (b + 1) + q;
                if (nt < 16) {
                    f16x8 bh = __builtin_bit_cast(f16x8, pbh[q]);
                    f16x8 bl = __builtin_bit_cast(f16x8, pbl[q]);
                    f32x4 d = (f32x4){0.f, 0.f, 0.f, 0.f};
                    d = __builtin_amdgcn_mfma_f32_16x16x32_f16(ah, bh, d, 0, 0, 0);
                    d = __builtin_amdgcn_mfma_f32_16x16x32_f16(al, bh, d, 0, 0, 0);
                    d = __builtin_amdgcn_mfma_f32_16x16x32_f16(ah, bl, d, 0, 0, 0);
                    #pragma unroll
                    for (int jj = 0; jj < 4; ++jj) {
                        int idx = (g * 4 + jj) * 260 + nt * 16 + l15;
                        conacc[idx] += d[jj];
                    }
                }
            }
            // remaining nt load inline
            for (int nt = 2 * (b + 1) + 4; nt < 16; ++nt) {
                const size_t wrow = (size_t)(nt * 16 + l15 - 1) * 256 + b * 32 + g * 8;
                f16x8 bh = __builtin_bit_cast(f16x8, *reinterpret_cast<const u16x8*>(wnl_h + wrow));
                f16x8 bl = __builtin_bit_cast(f16x8, *reinterpret_cast<const u16x8*>(wnl_l + wrow));
                f32x4 d = (f32x4){0.f, 0.f, 0.f, 0.f};
                d = __builtin_amdgcn_mfma_f32_16x16x32_f16(ah, bh, d, 0, 0, 0);
                d = __builtin_amdgcn_mfma_f32_16x16x32_f16(al, bh, d, 0, 0, 0);
                d = __builtin_amdgcn_mfma_f32_16x16x32_f16(ah, bl, d, 0, 0, 0);
                #pragma unroll
                for (int jj = 0; jj < 4; ++jj) {
                    int idx = (g * 4 + jj) * 260 + nt * 16 + l15;
                    conacc[idx] += d[jj];
                }
            }
        }
        __syncthreads();   // updates visible before next serial window / stage 3
    }

    // ===== stage 3: out = tanh @ W_out^T + lin_o + 1 (A-frags from conacc) =====
    #pragma unroll
    for (int n = 0; n < 4; ++n) {
        f32x4 acc = (f32x4){0.f, 0.f, 0.f, 0.f};
        #pragma unroll
        for (int kc = 0; kc < 8; ++kc) {
            const unsigned int* p = &conp[l15 * 260 + kc * 32 + g * 8];
            f16x8 ah, al;
            unpack_pf(*reinterpret_cast<const u32x4*>(p),
                      *reinterpret_cast<const u32x4*>(p + 4), &ah, &al);
            const size_t wrow = (size_t)(n * 16 + l15) * 256 + kc * 32 + g * 8;
            f16x8 bh = __builtin_bit_cast(f16x8, *reinterpret_cast<const u16x8*>(wout_h + wrow));
            f16x8 bl = __builtin_bit_cast(f16x8, *reinterpret_cast<const u16x8*>(wout_l + wrow));
            acc = __builtin_amdgcn_mfma_f32_16x16x32_f16(ah, bh, acc, 0, 0, 0);
            acc = __builtin_amdgcn_mfma_f32_16x16x32_f16(al, bh, acc, 0, 0, 0);
            acc = __builtin_amdgcn_mfma_f32_16x16x32_f16(ah, bl, acc, 0, 0, 0);
        }
        #pragma unroll
        for (int j = 0; j < 4; ++j) {
            long rr = row0 + g * 4 + j;
            int c = n * 16 + l15;
            out[rr * 64 + c] = acc[j] + lino[rr * 64 + c] + 1.0f;
        }
    }
}

extern "C" void kernel_launch(void* const* d_in, const int* in_sizes, int n_in,
                              void* d_out, int out_size, void* d_ws, size_t ws_size,
                              hipStream_t stream) {
    (void)in_sizes; (void)n_in; (void)out_size; (void)ws_size;
    const float* x     = (const float*)d_in[0];
    const float* W_lin = (const float*)d_in[1];
    const float* W_nl  = (const float*)d_in[2];
    const float* W_out = (const float*)d_in[3];
    float* out = (float*)d_out;

    char* ws = (char*)d_ws;
    unsigned short* wlin_h = (unsigned short*)(ws);
    unsigned short* wlin_l = (unsigned short*)(ws + 327680);
    unsigned short* wnl_h  = (unsigned short*)(ws + 916480);
    unsigned short* wnl_l  = (unsigned short*)(ws + 1047040);
    unsigned short* wout_h = (unsigned short*)(ws + 1177600);
    unsigned short* wout_l = (unsigned short*)(ws + 1210368);
    float*          wcol   = (float*)(ws + 1243136);
    float*          linc   = (float*)(ws + 1259008);
    float*          lino   = (float*)(ws + 68367872);

    cascade_prep<<<256, 256, 0, stream>>>(W_lin, W_nl, W_out,
                                          wlin_h, wlin_l, wnl_h, wnl_l,
                                          wout_h, wout_l, wcol);
    lin_gemm<<<512, 512, 0, stream>>>(x, wlin_h, wlin_l, linc, lino);
    cascade_casc<<<4096, 64, 0, stream>>>(linc, lino, wcol,
                                          wnl_h, wnl_l, wout_h, wout_l, out);
}

// Round 26
// 224.674 us; speedup vs baseline: 2.0524x; 1.0559x over previous
//
#include <hip/hip_runtime.h>
#include <hip/hip_bf16.h>

typedef _Float16 f16x8 __attribute__((ext_vector_type(8)));
typedef unsigned short u16x8 __attribute__((ext_vector_type(8)));
typedef float f32x4 __attribute__((ext_vector_type(4)));
typedef unsigned int u32x4 __attribute__((ext_vector_type(4)));

static __device__ __forceinline__ unsigned short h2u(_Float16 h) {
    return __builtin_bit_cast(unsigned short, h);
}
// tanh(x) = 1 - 2/(exp(2x)+1). v26: IEEE divide replaced with v_rcp_f32
// (~1ulp, single instruction) — the divide's ~10-inst sequence sat in the
// 256-step serial dependency chain. Saturation exact at both extremes:
// e->inf => rcp->0 => 1;  e->0 => 1-2 = -1.
static __device__ __forceinline__ float fast_tanh(float x) {
    float e = __expf(2.0f * x);
    return 1.0f - 2.0f * __builtin_amdgcn_rcpf(e + 1.0f);
}

// ---------------- ws layout (bytes) ----------------
//   wlin_h : u16 [320][512]   @ 0        (327680)
//   wlin_l : u16 [320][512]   @ 327680   (327680)
//   (unused)                  @ 655360   (261120)
//   wnl_h  : u16 [255][256]   @ 916480   (130560)
//   wnl_l  : u16 [255][256]   @ 1047040  (130560)
//   wout_h : u16 [64][256]    @ 1177600  (32768)
//   wout_l : u16 [64][256]    @ 1210368  (32768)
//   wcol   : f32 [8][496]     @ 1243136  (15872)
//   linc   : f32 [65536][256] @ 1259008  (67108864)  COLUMN-SHIFTED lin
//   lino   : f32 [65536][64]  @ 68367872 (16777216)  total 85145088
__global__ void cascade_prep(const float* __restrict__ W_lin,
                             const float* __restrict__ W_nl,
                             const float* __restrict__ W_out,
                             unsigned short* __restrict__ wlin_h,
                             unsigned short* __restrict__ wlin_l,
                             unsigned short* __restrict__ wnl_h,
                             unsigned short* __restrict__ wnl_l,
                             unsigned short* __restrict__ wout_h,
                             unsigned short* __restrict__ wout_l,
                             float* __restrict__ wcol) {
    int idx = blockIdx.x * blockDim.x + threadIdx.x;
    int stride = gridDim.x * blockDim.x;
    for (int i = idx; i < 320 * 512; i += stride) {
        int n = i >> 9, k = i & 511;
        float w = W_lin[k * 320 + n];
        _Float16 h = (_Float16)w;
        wlin_h[i] = h2u(h);
        wlin_l[i] = h2u((_Float16)(w - (float)h));
    }
    for (int i = idx; i < 255 * 256; i += stride) {
        int r = i >> 8, k = i & 255;
        float w = (k <= r) ? W_nl[i] : 0.0f;
        _Float16 h = (_Float16)w;
        wnl_h[i] = h2u(h);
        wnl_l[i] = h2u((_Float16)(w - (float)h));
    }
    for (int i = idx; i < 64 * 256; i += stride) {
        float w = W_out[i];
        _Float16 h = (_Float16)w;
        wout_h[i] = h2u(h);
        wout_l[i] = h2u((_Float16)(w - (float)h));
    }
    for (int i = idx; i < 256; i += stride) {
        int b = i >> 5, u = i & 31;
        float* dst = wcol + b * 496 + (31 * u - (u * (u - 1)) / 2);
        for (int j = u + 1; j < 32; ++j)
            dst[j - u - 1] = W_nl[(size_t)(b * 32 + j - 1) * 256 + b * 32 + u];
    }
}

// ---------------- kernel A: lin = x @ W_lin (fp16-split) ----------------
// Writes linc COLUMN-SHIFTED: linc[r][c+1] = lin[r][c] (c<255), linc[r][0] =
// lin[r][0]. casc's conacc[j] = lin[j-1] + contrib[j] aligns per-column.
__global__ __launch_bounds__(512, 1) void lin_gemm(
    const float* __restrict__ x,
    const unsigned short* __restrict__ wlin_h,
    const unsigned short* __restrict__ wlin_l,
    float* __restrict__ linc,
    float* __restrict__ lino) {

    __shared__ _Float16 bufH[2][16 * 520];
    __shared__ _Float16 bufL[2][16 * 520];

    const int tid = threadIdx.x;
    const int wv  = tid >> 6;
    const int l15 = tid & 15;
    const int g   = (tid & 63) >> 4;
    const int s = (blockIdx.x & 7) * 64 + (blockIdx.x >> 3);   // XCD chunking
    const long row0 = (long)s * 128;

    f16x8 xfh[16], xfl[16];
    {
        const float* xp = x + (row0 + wv * 16 + l15) * 512 + g * 8;
        #pragma unroll
        for (int ks = 0; ks < 16; ++ks) {
            float4 p0 = *reinterpret_cast<const float4*>(xp + ks * 32);
            float4 p1 = *reinterpret_cast<const float4*>(xp + ks * 32 + 4);
            float av[8] = {p0.x, p0.y, p0.z, p0.w, p1.x, p1.y, p1.z, p1.w};
            f16x8 fh, fl;
            #pragma unroll
            for (int e = 0; e < 8; ++e) {
                _Float16 hh = (_Float16)av[e];
                fh[e] = hh;
                fl[e] = (_Float16)(av[e] - (float)hh);
            }
            xfh[ks] = fh;
            xfl[ks] = fl;
        }
    }

    u16x8 rh[2], rl[2];
    #define STAGE_LOAD(nt)                                                     \
        {                                                                      \
            _Pragma("unroll")                                                  \
            for (int it = 0; it < 2; ++it) {                                   \
                int flat = it * 4096 + tid * 8;                                \
                int r = flat >> 9, c = flat & 511;                             \
                rh[it] = *reinterpret_cast<const u16x8*>(                      \
                    wlin_h + (size_t)((nt) * 16 + r) * 512 + c);               \
                rl[it] = *reinterpret_cast<const u16x8*>(                      \
                    wlin_l + (size_t)((nt) * 16 + r) * 512 + c);               \
            }                                                                  \
        }
    #define STAGE_WRITE(buf)                                                   \
        {                                                                      \
            _Pragma("unroll")                                                  \
            for (int it = 0; it < 2; ++it) {                                   \
                int flat = it * 4096 + tid * 8;                                \
                int r = flat >> 9, c = flat & 511;                             \
                *reinterpret_cast<u16x8*>(&bufH[buf][r * 520 + c]) =           \
                    __builtin_bit_cast(u16x8, rh[it]);                         \
                *reinterpret_cast<u16x8*>(&bufL[buf][r * 520 + c]) =           \
                    __builtin_bit_cast(u16x8, rl[it]);                         \
            }                                                                  \
        }

    STAGE_LOAD(0);
    STAGE_WRITE(0);
    __syncthreads();

    int cur = 0;
    for (int nt = 0; nt < 20; ++nt) {
        if (nt < 19) STAGE_LOAD(nt + 1);

        f32x4 acc = (f32x4){0.f, 0.f, 0.f, 0.f};
        if (nt < 16) {
            #pragma unroll
            for (int ks = 0; ks < 16; ++ks) {
                f16x8 bh = *reinterpret_cast<const f16x8*>(
                    &bufH[cur][l15 * 520 + ks * 32 + g * 8]);
                f16x8 bl = *reinterpret_cast<const f16x8*>(
                    &bufL[cur][l15 * 520 + ks * 32 + g * 8]);
                acc = __builtin_amdgcn_mfma_f32_16x16x32_f16(xfh[ks], bh, acc, 0, 0, 0);
                acc = __builtin_amdgcn_mfma_f32_16x16x32_f16(xfl[ks], bh, acc, 0, 0, 0);
                acc = __builtin_amdgcn_mfma_f32_16x16x32_f16(xfh[ks], bl, acc, 0, 0, 0);
            }
            int c = nt * 16 + l15;
            #pragma unroll
            for (int j = 0; j < 4; ++j) {
                long row = row0 + wv * 16 + g * 4 + j;
                if (c < 255) linc[row * 256 + c + 1] = acc[j];
                if (c == 0)  linc[row * 256] = acc[j];
            }
        } else {
            #pragma unroll
            for (int ks = 0; ks < 16; ++ks) {
                f16x8 bh = *reinterpret_cast<const f16x8*>(
                    &bufH[cur][l15 * 520 + ks * 32 + g * 8]);
                acc = __builtin_amdgcn_mfma_f32_16x16x32_f16(xfh[ks], bh, acc, 0, 0, 0);
            }
            #pragma unroll
            for (int j = 0; j < 4; ++j)
                lino[(row0 + wv * 16 + g * 4 + j) * 64 + (nt - 16) * 16 + l15] = acc[j];
        }

        if (nt < 19) STAGE_WRITE(cur ^ 1);
        __syncthreads();
        cur ^= 1;
    }
    #undef STAGE_LOAD
    #undef STAGE_WRITE
}

// unpack packed h|l u32x4 pair -> fp16 hi / lo MFMA A-fragments
static __device__ __forceinline__ void unpack_pf(u32x4 a0, u32x4 a1,
                                                 f16x8* ah, f16x8* al) {
    u32x4 hx, lx;
    hx[0] = (a0[0] & 0xffffu) | (a0[1] << 16);
    hx[1] = (a0[2] & 0xffffu) | (a0[3] << 16);
    hx[2] = (a1[0] & 0xffffu) | (a1[1] << 16);
    hx[3] = (a1[2] & 0xffffu) | (a1[3] << 16);
    lx[0] = (a0[0] >> 16) | (a0[1] & 0xffff0000u);
    lx[1] = (a0[2] >> 16) | (a0[3] & 0xffff0000u);
    lx[2] = (a1[0] >> 16) | (a1[1] & 0xffff0000u);
    lx[3] = (a1[2] >> 16) | (a1[3] & 0xffff0000u);
    *ah = __builtin_bit_cast(f16x8, hx);
    *al = __builtin_bit_cast(f16x8, lx);
}

// ---------------- kernel B: forward-accumulating cascade, 16 rows/block ----------------
// r21 structure (best stable) + rcp-tanh. The serial cascade survives ONLY as
// a 1-wave, unconstrained-bounds, <=~120-VGPR body (r7/r16/r20/r23/r24 lessons).
// 16 rows/block, 8 independent blocks/CU, grid 4096, XCD chunk 512.
__global__ __launch_bounds__(64) void cascade_casc(
    const float* __restrict__ linc,
    const float* __restrict__ lino,
    const float* __restrict__ wcol,
    const unsigned short* __restrict__ wnl_h,
    const unsigned short* __restrict__ wnl_l,
    const unsigned short* __restrict__ wout_h,
    const unsigned short* __restrict__ wout_l,
    float* __restrict__ out) {

    __shared__ float conacc[16 * 260];   // [row][col], stride 260
    __shared__ float wslab[500];         // intra-block triangle slab
    unsigned int* conp = reinterpret_cast<unsigned int*>(conacc);

    const int l   = threadIdx.x;
    const int l15 = l & 15;
    const int g   = l >> 4;          // MFMA k-group / serial replica id
    const int s = (blockIdx.x & 7) * 512 + (blockIdx.x >> 3);   // XCD chunking
    const long row0 = (long)s * 16;

    // ===== init conacc = linc (shifted lin): 4096 floats / 64 lanes =====
    #pragma unroll
    for (int it = 0; it < 16; ++it) {
        int flat = it * 256 + l * 4;
        int rr = flat >> 8, c4 = flat & 255;
        float4 v = *reinterpret_cast<const float4*>(linc + (row0 + rr) * 256 + c4);
        *reinterpret_cast<float4*>(&conacc[rr * 260 + c4]) = v;
    }
    __syncthreads();

    for (int b = 0; b < 8; ++b) {
        // --- T14: prefetch first 4 nt-iterations' wnl fragments (static idx) ---
        u16x8 pbh[4], pbl[4];
        if (b < 7) {
            #pragma unroll
            for (int q = 0; q < 4; ++q) {
                int nt = 2 * (b + 1) + q;
                if (nt < 16) {
                    const size_t wrow = (size_t)(nt * 16 + l15 - 1) * 256 + b * 32 + g * 8;
                    pbh[q] = *reinterpret_cast<const u16x8*>(wnl_h + wrow);
                    pbl[q] = *reinterpret_cast<const u16x8*>(wnl_l + wrow);
                }
            }
        }

        // --- stage wcol slab for block b (broadcast ds_read path) ---
        {
            int i0 = l * 4;
            float4 v0 = *reinterpret_cast<const float4*>(wcol + b * 496 + i0);
            *reinterpret_cast<float4*>(&wslab[i0]) = v0;      // i0 in [0,252]
            int i1 = 256 + l * 4;
            if (i1 < 496) {
                float4 v1 = *reinterpret_cast<const float4*>(wcol + b * 496 + i1);
                *reinterpret_cast<float4*>(&wslab[i1]) = v1;
            }
        }
        __syncthreads();   // wslab ready; prev MFMA-pass conacc updates visible

        // --- serial 32 steps (4 replicas of each row's chain) ---
        float acc[32];
        #pragma unroll
        for (int j = 0; j < 32; ++j) acc[j] = 0.0f;
        #pragma unroll
        for (int u8 = 0; u8 < 4; ++u8) {
            float4 cw0 = *reinterpret_cast<const float4*>(&conacc[l15 * 260 + b * 32 + u8 * 8]);
            float4 cw1 = *reinterpret_cast<const float4*>(&conacc[l15 * 260 + b * 32 + u8 * 8 + 4]);
            float conw[8] = {cw0.x, cw0.y, cw0.z, cw0.w, cw1.x, cw1.y, cw1.z, cw1.w};
            unsigned int pk[8];
            #pragma unroll
            for (int v = 0; v < 8; ++v) {
                const int u = u8 * 8 + v;
                float vv = acc[u] + conw[v] + 1.0f;
                float tv = fast_tanh(vv);
                _Float16 hv = (_Float16)tv;
                _Float16 lo = (_Float16)(tv - (float)hv);
                pk[v] = (unsigned int)h2u(hv) | ((unsigned int)h2u(lo) << 16);
                const float* wu = wslab + (31 * u - (u * (u - 1)) / 2);
                #pragma unroll
                for (int j = u + 1; j < 32; ++j)
                    acc[j] = fmaf(tv, wu[j - u - 1], acc[j]);
            }
            // overwrite consumed cols with packed th (one replica writes)
            if (l < 16) {
                *reinterpret_cast<u32x4*>(&conp[l15 * 260 + b * 32 + u8 * 8]) =
                    (u32x4){pk[0], pk[1], pk[2], pk[3]};
                *reinterpret_cast<u32x4*>(&conp[l15 * 260 + b * 32 + u8 * 8 + 4]) =
                    (u32x4){pk[4], pk[5], pk[6], pk[7]};
            }
        }
        __syncthreads();   // packed th visible to all lanes

        // --- forward MFMA: conacc[:, 32(b+1):] += th_b @ Wnl^T ---
        if (b < 7) {
            f16x8 ah, al;
            {
                const unsigned int* p = &conp[l15 * 260 + b * 32 + g * 8];
                unpack_pf(*reinterpret_cast<const u32x4*>(p),
                          *reinterpret_cast<const u32x4*>(p + 4), &ah, &al);
            }
            // first up-to-4 nt from prefetched registers (static unroll)
            #pragma unroll
            for (int q = 0; q < 4; ++q) {
                int nt = 2 * (b + 1) + q;
                if (nt < 16) {
                    f16x8 bh = __builtin_bit_cast(f16x8, pbh[q]);
                    f16x8 bl = __builtin_bit_cast(f16x8, pbl[q]);
                    f32x4 d = (f32x4){0.f, 0.f, 0.f, 0.f};
                    d = __builtin_amdgcn_mfma_f32_16x16x32_f16(ah, bh, d, 0, 0, 0);
                    d = __builtin_amdgcn_mfma_f32_16x16x32_f16(al, bh, d, 0, 0, 0);
                    d = __builtin_amdgcn_mfma_f32_16x16x32_f16(ah, bl, d, 0, 0, 0);
                    #pragma unroll
                    for (int jj = 0; jj < 4; ++jj) {
                        int idx = (g * 4 + jj) * 260 + nt * 16 + l15;
                        conacc[idx] += d[jj];
                    }
                }
            }
            // remaining nt load inline
            for (int nt = 2 * (b + 1) + 4; nt < 16; ++nt) {
                const size_t wrow = (size_t)(nt * 16 + l15 - 1) * 256 + b * 32 + g * 8;
                f16x8 bh = __builtin_bit_cast(f16x8, *reinterpret_cast<const u16x8*>(wnl_h + wrow));
                f16x8 bl = __builtin_bit_cast(f16x8, *reinterpret_cast<const u16x8*>(wnl_l + wrow));
                f32x4 d = (f32x4){0.f, 0.f, 0.f, 0.f};
                d = __builtin_amdgcn_mfma_f32_16x16x32_f16(ah, bh, d, 0, 0, 0);
                d = __builtin_amdgcn_mfma_f32_16x16x32_f16(al, bh, d, 0, 0, 0);
                d = __builtin_amdgcn_mfma_f32_16x16x32_f16(ah, bl, d, 0, 0, 0);
                #pragma unroll
                for (int jj = 0; jj < 4; ++jj) {
                    int idx = (g * 4 + jj) * 260 + nt * 16 + l15;
                    conacc[idx] += d[jj];
                }
            }
        }
        __syncthreads();   // updates visible before next serial window / stage 3
    }

    // ===== stage 3: out = tanh @ W_out^T + lin_o + 1 (A-frags from conacc) =====
    #pragma unroll
    for (int n = 0; n < 4; ++n) {
        f32x4 acc = (f32x4){0.f, 0.f, 0.f, 0.f};
        #pragma unroll
        for (int kc = 0; kc < 8; ++kc) {
            const unsigned int* p = &conp[l15 * 260 + kc * 32 + g * 8];
            f16x8 ah, al;
            unpack_pf(*reinterpret_cast<const u32x4*>(p),
                      *reinterpret_cast<const u32x4*>(p + 4), &ah, &al);
            const size_t wrow = (size_t)(n * 16 + l15) * 256 + kc * 32 + g * 8;
            f16x8 bh = __builtin_bit_cast(f16x8, *reinterpret_cast<const u16x8*>(wout_h + wrow));
            f16x8 bl = __builtin_bit_cast(f16x8, *reinterpret_cast<const u16x8*>(wout_l + wrow));
            acc = __builtin_amdgcn_mfma_f32_16x16x32_f16(ah, bh, acc, 0, 0, 0);
            acc = __builtin_amdgcn_mfma_f32_16x16x32_f16(al, bh, acc, 0, 0, 0);
            acc = __builtin_amdgcn_mfma_f32_16x16x32_f16(ah, bl, acc, 0, 0, 0);
        }
        #pragma unroll
        for (int j = 0; j < 4; ++j) {
            long rr = row0 + g * 4 + j;
            int c = n * 16 + l15;
            out[rr * 64 + c] = acc[j] + lino[rr * 64 + c] + 1.0f;
        }
    }
}

extern "C" void kernel_launch(void* const* d_in, const int* in_sizes, int n_in,
                              void* d_out, int out_size, void* d_ws, size_t ws_size,
                              hipStream_t stream) {
    (void)in_sizes; (void)n_in; (void)out_size; (void)ws_size;
    const float* x     = (const float*)d_in[0];
    const float* W_lin = (const float*)d_in[1];
    const float* W_nl  = (const float*)d_in[2];
    const float* W_out = (const float*)d_in[3];
    float* out = (float*)d_out;

    char* ws = (char*)d_ws;
    unsigned short* wlin_h = (unsigned short*)(ws);
    unsigned short* wlin_l = (unsigned short*)(ws + 327680);
    unsigned short* wnl_h  = (unsigned short*)(ws + 916480);
    unsigned short* wnl_l  = (unsigned short*)(ws + 1047040);
    unsigned short* wout_h = (unsigned short*)(ws + 1177600);
    unsigned short* wout_l = (unsigned short*)(ws + 1210368);
    float*          wcol   = (float*)(ws + 1243136);
    float*          linc   = (float*)(ws + 1259008);
    float*          lino   = (float*)(ws + 68367872);

    cascade_prep<<<256, 256, 0, stream>>>(W_lin, W_nl, W_out,
                                          wlin_h, wlin_l, wnl_h, wnl_l,
                                          wout_h, wout_l, wcol);
    lin_gemm<<<512, 512, 0, stream>>>(x, wlin_h, wlin_l, linc, lino);
    cascade_casc<<<4096, 64, 0, stream>>>(linc, lino, wcol,
                                          wnl_h, wnl_l, wout_h, wout_l, out);
}

// Round 27
// 223.765 us; speedup vs baseline: 2.0607x; 1.0041x over previous
//
#include <hip/hip_runtime.h>
#include <hip/hip_bf16.h>

typedef _Float16 f16x8 __attribute__((ext_vector_type(8)));
typedef unsigned short u16x8 __attribute__((ext_vector_type(8)));
typedef float f32x4 __attribute__((ext_vector_type(4)));
typedef unsigned int u32x4 __attribute__((ext_vector_type(4)));

static __device__ __forceinline__ unsigned short h2u(_Float16 h) {
    return __builtin_bit_cast(unsigned short, h);
}
// tanh(x) = 1 - 2/(exp(2x)+1), minimal-chain form:
//   t = x * (2*log2(e))  [1 mul] -> e = 2^t [v_exp] -> +1 -> v_rcp
//   -> fmaf(-2, r, 1)    [1 fma]
// r26's v_rcp replaced the IEEE divide (-16us); r27 folds the two constant
// muls into one and the final mul+sub into one fma.
static __device__ __forceinline__ float fast_tanh(float x) {
    float t = x * 2.885390082f;          // 2 * log2(e)
#if __has_builtin(__builtin_amdgcn_exp2f)
    float e = __builtin_amdgcn_exp2f(t);
#else
    float e = exp2f(t);
#endif
    float r = __builtin_amdgcn_rcpf(e + 1.0f);
    return fmaf(-2.0f, r, 1.0f);
}

// ---------------- ws layout (bytes) ----------------
//   wlin_h : u16 [320][512]   @ 0        (327680)
//   wlin_l : u16 [320][512]   @ 327680   (327680)
//   (unused)                  @ 655360   (261120)
//   wnl_h  : u16 [255][256]   @ 916480   (130560)
//   wnl_l  : u16 [255][256]   @ 1047040  (130560)
//   wout_h : u16 [64][256]    @ 1177600  (32768)
//   wout_l : u16 [64][256]    @ 1210368  (32768)
//   wcol   : f32 [8][496]     @ 1243136  (15872)
//   linc   : f32 [65536][256] @ 1259008  (67108864)  COLUMN-SHIFTED lin
//   lino   : f32 [65536][64]  @ 68367872 (16777216)  total 85145088
__global__ void cascade_prep(const float* __restrict__ W_lin,
                             const float* __restrict__ W_nl,
                             const float* __restrict__ W_out,
                             unsigned short* __restrict__ wlin_h,
                             unsigned short* __restrict__ wlin_l,
                             unsigned short* __restrict__ wnl_h,
                             unsigned short* __restrict__ wnl_l,
                             unsigned short* __restrict__ wout_h,
                             unsigned short* __restrict__ wout_l,
                             float* __restrict__ wcol) {
    int idx = blockIdx.x * blockDim.x + threadIdx.x;
    int stride = gridDim.x * blockDim.x;
    for (int i = idx; i < 320 * 512; i += stride) {
        int n = i >> 9, k = i & 511;
        float w = W_lin[k * 320 + n];
        _Float16 h = (_Float16)w;
        wlin_h[i] = h2u(h);
        wlin_l[i] = h2u((_Float16)(w - (float)h));
    }
    for (int i = idx; i < 255 * 256; i += stride) {
        int r = i >> 8, k = i & 255;
        float w = (k <= r) ? W_nl[i] : 0.0f;
        _Float16 h = (_Float16)w;
        wnl_h[i] = h2u(h);
        wnl_l[i] = h2u((_Float16)(w - (float)h));
    }
    for (int i = idx; i < 64 * 256; i += stride) {
        float w = W_out[i];
        _Float16 h = (_Float16)w;
        wout_h[i] = h2u(h);
        wout_l[i] = h2u((_Float16)(w - (float)h));
    }
    for (int i = idx; i < 256; i += stride) {
        int b = i >> 5, u = i & 31;
        float* dst = wcol + b * 496 + (31 * u - (u * (u - 1)) / 2);
        for (int j = u + 1; j < 32; ++j)
            dst[j - u - 1] = W_nl[(size_t)(b * 32 + j - 1) * 256 + b * 32 + u];
    }
}

// ---------------- kernel A: lin = x @ W_lin (fp16-split) ----------------
// Writes linc COLUMN-SHIFTED: linc[r][c+1] = lin[r][c] (c<255), linc[r][0] =
// lin[r][0]. casc's conacc[j] = lin[j-1] + contrib[j] aligns per-column.
__global__ __launch_bounds__(512, 1) void lin_gemm(
    const float* __restrict__ x,
    const unsigned short* __restrict__ wlin_h,
    const unsigned short* __restrict__ wlin_l,
    float* __restrict__ linc,
    float* __restrict__ lino) {

    __shared__ _Float16 bufH[2][16 * 520];
    __shared__ _Float16 bufL[2][16 * 520];

    const int tid = threadIdx.x;
    const int wv  = tid >> 6;
    const int l15 = tid & 15;
    const int g   = (tid & 63) >> 4;
    const int s = (blockIdx.x & 7) * 64 + (blockIdx.x >> 3);   // XCD chunking
    const long row0 = (long)s * 128;

    f16x8 xfh[16], xfl[16];
    {
        const float* xp = x + (row0 + wv * 16 + l15) * 512 + g * 8;
        #pragma unroll
        for (int ks = 0; ks < 16; ++ks) {
            float4 p0 = *reinterpret_cast<const float4*>(xp + ks * 32);
            float4 p1 = *reinterpret_cast<const float4*>(xp + ks * 32 + 4);
            float av[8] = {p0.x, p0.y, p0.z, p0.w, p1.x, p1.y, p1.z, p1.w};
            f16x8 fh, fl;
            #pragma unroll
            for (int e = 0; e < 8; ++e) {
                _Float16 hh = (_Float16)av[e];
                fh[e] = hh;
                fl[e] = (_Float16)(av[e] - (float)hh);
            }
            xfh[ks] = fh;
            xfl[ks] = fl;
        }
    }

    u16x8 rh[2], rl[2];
    #define STAGE_LOAD(nt)                                                     \
        {                                                                      \
            _Pragma("unroll")                                                  \
            for (int it = 0; it < 2; ++it) {                                   \
                int flat = it * 4096 + tid * 8;                                \
                int r = flat >> 9, c = flat & 511;                             \
                rh[it] = *reinterpret_cast<const u16x8*>(                      \
                    wlin_h + (size_t)((nt) * 16 + r) * 512 + c);               \
                rl[it] = *reinterpret_cast<const u16x8*>(                      \
                    wlin_l + (size_t)((nt) * 16 + r) * 512 + c);               \
            }                                                                  \
        }
    #define STAGE_WRITE(buf)                                                   \
        {                                                                      \
            _Pragma("unroll")                                                  \
            for (int it = 0; it < 2; ++it) {                                   \
                int flat = it * 4096 + tid * 8;                                \
                int r = flat >> 9, c = flat & 511;                             \
                *reinterpret_cast<u16x8*>(&bufH[buf][r * 520 + c]) =           \
                    __builtin_bit_cast(u16x8, rh[it]);                         \
                *reinterpret_cast<u16x8*>(&bufL[buf][r * 520 + c]) =           \
                    __builtin_bit_cast(u16x8, rl[it]);                         \
            }                                                                  \
        }

    STAGE_LOAD(0);
    STAGE_WRITE(0);
    __syncthreads();

    int cur = 0;
    for (int nt = 0; nt < 20; ++nt) {
        if (nt < 19) STAGE_LOAD(nt + 1);

        f32x4 acc = (f32x4){0.f, 0.f, 0.f, 0.f};
        if (nt < 16) {
            #pragma unroll
            for (int ks = 0; ks < 16; ++ks) {
                f16x8 bh = *reinterpret_cast<const f16x8*>(
                    &bufH[cur][l15 * 520 + ks * 32 + g * 8]);
                f16x8 bl = *reinterpret_cast<const f16x8*>(
                    &bufL[cur][l15 * 520 + ks * 32 + g * 8]);
                acc = __builtin_amdgcn_mfma_f32_16x16x32_f16(xfh[ks], bh, acc, 0, 0, 0);
                acc = __builtin_amdgcn_mfma_f32_16x16x32_f16(xfl[ks], bh, acc, 0, 0, 0);
                acc = __builtin_amdgcn_mfma_f32_16x16x32_f16(xfh[ks], bl, acc, 0, 0, 0);
            }
            int c = nt * 16 + l15;
            #pragma unroll
            for (int j = 0; j < 4; ++j) {
                long row = row0 + wv * 16 + g * 4 + j;
                if (c < 255) linc[row * 256 + c + 1] = acc[j];
                if (c == 0)  linc[row * 256] = acc[j];
            }
        } else {
            #pragma unroll
            for (int ks = 0; ks < 16; ++ks) {
                f16x8 bh = *reinterpret_cast<const f16x8*>(
                    &bufH[cur][l15 * 520 + ks * 32 + g * 8]);
                acc = __builtin_amdgcn_mfma_f32_16x16x32_f16(xfh[ks], bh, acc, 0, 0, 0);
            }
            #pragma unroll
            for (int j = 0; j < 4; ++j)
                lino[(row0 + wv * 16 + g * 4 + j) * 64 + (nt - 16) * 16 + l15] = acc[j];
        }

        if (nt < 19) STAGE_WRITE(cur ^ 1);
        __syncthreads();
        cur ^= 1;
    }
    #undef STAGE_LOAD
    #undef STAGE_WRITE
}

// unpack packed h|l u32x4 pair -> fp16 hi / lo MFMA A-fragments
static __device__ __forceinline__ void unpack_pf(u32x4 a0, u32x4 a1,
                                                 f16x8* ah, f16x8* al) {
    u32x4 hx, lx;
    hx[0] = (a0[0] & 0xffffu) | (a0[1] << 16);
    hx[1] = (a0[2] & 0xffffu) | (a0[3] << 16);
    hx[2] = (a1[0] & 0xffffu) | (a1[1] << 16);
    hx[3] = (a1[2] & 0xffffu) | (a1[3] << 16);
    lx[0] = (a0[0] >> 16) | (a0[1] & 0xffff0000u);
    lx[1] = (a0[2] >> 16) | (a0[3] & 0xffff0000u);
    lx[2] = (a1[0] >> 16) | (a1[1] & 0xffff0000u);
    lx[3] = (a1[2] >> 16) | (a1[3] & 0xffff0000u);
    *ah = __builtin_bit_cast(f16x8, hx);
    *al = __builtin_bit_cast(f16x8, lx);
}

// ---------------- kernel B: forward-accumulating cascade, 16 rows/block ----------------
// r21 structure + rcp-tanh (r26, -16us) + chain trim (r27): single-constant
// exp2 mul, fma(-2,r,1), conw+1 hoisted off-chain. The serial cascade
// survives ONLY as a 1-wave, unconstrained-bounds, <=~120-VGPR body
// (r7/r16/r20/r23/r24 lessons). 16 rows/block, 8 independent blocks/CU,
// grid 4096, XCD chunk 512.
__global__ __launch_bounds__(64) void cascade_casc(
    const float* __restrict__ linc,
    const float* __restrict__ lino,
    const float* __restrict__ wcol,
    const unsigned short* __restrict__ wnl_h,
    const unsigned short* __restrict__ wnl_l,
    const unsigned short* __restrict__ wout_h,
    const unsigned short* __restrict__ wout_l,
    float* __restrict__ out) {

    __shared__ float conacc[16 * 260];   // [row][col], stride 260
    __shared__ float wslab[500];         // intra-block triangle slab
    unsigned int* conp = reinterpret_cast<unsigned int*>(conacc);

    const int l   = threadIdx.x;
    const int l15 = l & 15;
    const int g   = l >> 4;          // MFMA k-group / serial replica id
    const int s = (blockIdx.x & 7) * 512 + (blockIdx.x >> 3);   // XCD chunking
    const long row0 = (long)s * 16;

    // ===== init conacc = linc (shifted lin): 4096 floats / 64 lanes =====
    #pragma unroll
    for (int it = 0; it < 16; ++it) {
        int flat = it * 256 + l * 4;
        int rr = flat >> 8, c4 = flat & 255;
        float4 v = *reinterpret_cast<const float4*>(linc + (row0 + rr) * 256 + c4);
        *reinterpret_cast<float4*>(&conacc[rr * 260 + c4]) = v;
    }
    __syncthreads();

    for (int b = 0; b < 8; ++b) {
        // --- T14: prefetch first 4 nt-iterations' wnl fragments (static idx) ---
        u16x8 pbh[4], pbl[4];
        if (b < 7) {
            #pragma unroll
            for (int q = 0; q < 4; ++q) {
                int nt = 2 * (b + 1) + q;
                if (nt < 16) {
                    const size_t wrow = (size_t)(nt * 16 + l15 - 1) * 256 + b * 32 + g * 8;
                    pbh[q] = *reinterpret_cast<const u16x8*>(wnl_h + wrow);
                    pbl[q] = *reinterpret_cast<const u16x8*>(wnl_l + wrow);
                }
            }
        }

        // --- stage wcol slab for block b (broadcast ds_read path) ---
        {
            int i0 = l * 4;
            float4 v0 = *reinterpret_cast<const float4*>(wcol + b * 496 + i0);
            *reinterpret_cast<float4*>(&wslab[i0]) = v0;      // i0 in [0,252]
            int i1 = 256 + l * 4;
            if (i1 < 496) {
                float4 v1 = *reinterpret_cast<const float4*>(wcol + b * 496 + i1);
                *reinterpret_cast<float4*>(&wslab[i1]) = v1;
            }
        }
        __syncthreads();   // wslab ready; prev MFMA-pass conacc updates visible

        // --- serial 32 steps (4 replicas of each row's chain) ---
        float acc[32];
        #pragma unroll
        for (int j = 0; j < 32; ++j) acc[j] = 0.0f;
        #pragma unroll
        for (int u8 = 0; u8 < 4; ++u8) {
            float4 cw0 = *reinterpret_cast<const float4*>(&conacc[l15 * 260 + b * 32 + u8 * 8]);
            float4 cw1 = *reinterpret_cast<const float4*>(&conacc[l15 * 260 + b * 32 + u8 * 8 + 4]);
            // +1 folded here, OFF the dependency chain (conw available early)
            float conw[8] = {cw0.x + 1.0f, cw0.y + 1.0f, cw0.z + 1.0f, cw0.w + 1.0f,
                             cw1.x + 1.0f, cw1.y + 1.0f, cw1.z + 1.0f, cw1.w + 1.0f};
            unsigned int pk[8];
            #pragma unroll
            for (int v = 0; v < 8; ++v) {
                const int u = u8 * 8 + v;
                float vv = acc[u] + conw[v];
                float tv = fast_tanh(vv);
                _Float16 hv = (_Float16)tv;
                _Float16 lo = (_Float16)(tv - (float)hv);
                pk[v] = (unsigned int)h2u(hv) | ((unsigned int)h2u(lo) << 16);
                const float* wu = wslab + (31 * u - (u * (u - 1)) / 2);
                #pragma unroll
                for (int j = u + 1; j < 32; ++j)
                    acc[j] = fmaf(tv, wu[j - u - 1], acc[j]);
            }
            // overwrite consumed cols with packed th (one replica writes)
            if (l < 16) {
                *reinterpret_cast<u32x4*>(&conp[l15 * 260 + b * 32 + u8 * 8]) =
                    (u32x4){pk[0], pk[1], pk[2], pk[3]};
                *reinterpret_cast<u32x4*>(&conp[l15 * 260 + b * 32 + u8 * 8 + 4]) =
                    (u32x4){pk[4], pk[5], pk[6], pk[7]};
            }
        }
        __syncthreads();   // packed th visible to all lanes

        // --- forward MFMA: conacc[:, 32(b+1):] += th_b @ Wnl^T ---
        if (b < 7) {
            f16x8 ah, al;
            {
                const unsigned int* p = &conp[l15 * 260 + b * 32 + g * 8];
                unpack_pf(*reinterpret_cast<const u32x4*>(p),
                          *reinterpret_cast<const u32x4*>(p + 4), &ah, &al);
            }
            // first up-to-4 nt from prefetched registers (static unroll)
            #pragma unroll
            for (int q = 0; q < 4; ++q) {
                int nt = 2 * (b + 1) + q;
                if (nt < 16) {
                    f16x8 bh = __builtin_bit_cast(f16x8, pbh[q]);
                    f16x8 bl = __builtin_bit_cast(f16x8, pbl[q]);
                    f32x4 d = (f32x4){0.f, 0.f, 0.f, 0.f};
                    d = __builtin_amdgcn_mfma_f32_16x16x32_f16(ah, bh, d, 0, 0, 0);
                    d = __builtin_amdgcn_mfma_f32_16x16x32_f16(al, bh, d, 0, 0, 0);
                    d = __builtin_amdgcn_mfma_f32_16x16x32_f16(ah, bl, d, 0, 0, 0);
                    #pragma unroll
                    for (int jj = 0; jj < 4; ++jj) {
                        int idx = (g * 4 + jj) * 260 + nt * 16 + l15;
                        conacc[idx] += d[jj];
                    }
                }
            }
            // remaining nt load inline
            for (int nt = 2 * (b + 1) + 4; nt < 16; ++nt) {
                const size_t wrow = (size_t)(nt * 16 + l15 - 1) * 256 + b * 32 + g * 8;
                f16x8 bh = __builtin_bit_cast(f16x8, *reinterpret_cast<const u16x8*>(wnl_h + wrow));
                f16x8 bl = __builtin_bit_cast(f16x8, *reinterpret_cast<const u16x8*>(wnl_l + wrow));
                f32x4 d = (f32x4){0.f, 0.f, 0.f, 0.f};
                d = __builtin_amdgcn_mfma_f32_16x16x32_f16(ah, bh, d, 0, 0, 0);
                d = __builtin_amdgcn_mfma_f32_16x16x32_f16(al, bh, d, 0, 0, 0);
                d = __builtin_amdgcn_mfma_f32_16x16x32_f16(ah, bl, d, 0, 0, 0);
                #pragma unroll
                for (int jj = 0; jj < 4; ++jj) {
                    int idx = (g * 4 + jj) * 260 + nt * 16 + l15;
                    conacc[idx] += d[jj];
                }
            }
        }
        __syncthreads();   // updates visible before next serial window / stage 3
    }

    // ===== stage 3: out = tanh @ W_out^T + lin_o + 1 (A-frags from conacc) =====
    #pragma unroll
    for (int n = 0; n < 4; ++n) {
        f32x4 acc = (f32x4){0.f, 0.f, 0.f, 0.f};
        #pragma unroll
        for (int kc = 0; kc < 8; ++kc) {
            const unsigned int* p = &conp[l15 * 260 + kc * 32 + g * 8];
            f16x8 ah, al;
            unpack_pf(*reinterpret_cast<const u32x4*>(p),
                      *reinterpret_cast<const u32x4*>(p + 4), &ah, &al);
            const size_t wrow = (size_t)(n * 16 + l15) * 256 + kc * 32 + g * 8;
            f16x8 bh = __builtin_bit_cast(f16x8, *reinterpret_cast<const u16x8*>(wout_h + wrow));
            f16x8 bl = __builtin_bit_cast(f16x8, *reinterpret_cast<const u16x8*>(wout_l + wrow));
            acc = __builtin_amdgcn_mfma_f32_16x16x32_f16(ah, bh, acc, 0, 0, 0);
            acc = __builtin_amdgcn_mfma_f32_16x16x32_f16(al, bh, acc, 0, 0, 0);
            acc = __builtin_amdgcn_mfma_f32_16x16x32_f16(ah, bl, acc, 0, 0, 0);
        }
        #pragma unroll
        for (int j = 0; j < 4; ++j) {
            long rr = row0 + g * 4 + j;
            int c = n * 16 + l15;
            out[rr * 64 + c] = acc[j] + lino[rr * 64 + c] + 1.0f;
        }
    }
}

extern "C" void kernel_launch(void* const* d_in, const int* in_sizes, int n_in,
                              void* d_out, int out_size, void* d_ws, size_t ws_size,
                              hipStream_t stream) {
    (void)in_sizes; (void)n_in; (void)out_size; (void)ws_size;
    const float* x     = (const float*)d_in[0];
    const float* W_lin = (const float*)d_in[1];
    const float* W_nl  = (const float*)d_in[2];
    const float* W_out = (const float*)d_in[3];
    float* out = (float*)d_out;

    char* ws = (char*)d_ws;
    unsigned short* wlin_h = (unsigned short*)(ws);
    unsigned short* wlin_l = (unsigned short*)(ws + 327680);
    unsigned short* wnl_h  = (unsigned short*)(ws + 916480);
    unsigned short* wnl_l  = (unsigned short*)(ws + 1047040);
    unsigned short* wout_h = (unsigned short*)(ws + 1177600);
    unsigned short* wout_l = (unsigned short*)(ws + 1210368);
    float*          wcol   = (float*)(ws + 1243136);
    float*          linc   = (float*)(ws + 1259008);
    float*          lino   = (float*)(ws + 68367872);

    cascade_prep<<<256, 256, 0, stream>>>(W_lin, W_nl, W_out,
                                          wlin_h, wlin_l, wnl_h, wnl_l,
                                          wout_h, wout_l, wcol);
    lin_gemm<<<512, 512, 0, stream>>>(x, wlin_h, wlin_l, linc, lino);
    cascade_casc<<<4096, 64, 0, stream>>>(linc, lino, wcol,
                                          wnl_h, wnl_l, wout_h, wout_l, out);
}